// Round 12
// baseline (211.820 us; speedup 1.0000x reference)
//
#include <hip/hip_runtime.h>
#include <math.h>

// Problem constants
#define BB 8
#define TT 1024
#define CC 1024
#define HH 16
#define HKV 4
#define HD 64
#define MM (BB*TT)   // 8192
#define LOG2E 1.4426950408889634f

typedef __attribute__((ext_vector_type(8))) short bf16x8;
typedef __attribute__((ext_vector_type(4))) float f32x4;

__device__ __forceinline__ float b2f(unsigned short x){
    union{unsigned int i; float f;} u; u.i = ((unsigned int)x)<<16; return u.f;
}
__device__ __forceinline__ unsigned short f2b(float f){
    union{float f; unsigned int i;} u; u.f = f;
    unsigned int r = u.i + 0x7fffu + ((u.i>>16)&1u);
    return (unsigned short)(r>>16);
}

// async 16B global -> LDS (gfx950 global_load_lds_dwordx4)
#define GLD16(gp, lp) __builtin_amdgcn_global_load_lds( \
    (__attribute__((address_space(1))) void*)(gp), \
    (__attribute__((address_space(3))) void*)(lp), 16, 0, 0)

// ---------------- fp32 -> bf16 conversion (all inputs, one kernel) ----------
__global__ __launch_bounds__(256) void cvt_all(const float* __restrict__ x,
                                               const float* __restrict__ w_q,
                                               const float* __restrict__ w_kv,
                                               const float* __restrict__ w_c,
                                               unsigned short* __restrict__ xb,
                                               unsigned short* __restrict__ wqkvb,
                                               unsigned short* __restrict__ wcb){
    int i = blockIdx.x*256 + threadIdx.x;
    const float* src; unsigned short* dst; int off;
    if (i < 2097152)      { src = x;    dst = xb;              off = i; }
    else if (i < 2359296) { src = w_q;  dst = wqkvb;           off = i - 2097152; }
    else if (i < 2490368) { src = w_kv; dst = wqkvb + 1048576; off = i - 2359296; }
    else                  { src = w_c;  dst = wcb;             off = i - 2490368; }
    float4 f = ((const float4*)src)[off];
    ushort4 o;
    o.x = f2b(f.x); o.y = f2b(f.y); o.z = f2b(f.z); o.w = f2b(f.w);
    ((ushort4*)dst)[off] = o;
}

// ---------------- bf16 MFMA GEMM: C = A(MxK) * Bt(NxK)^T ---------------------
// T1 XCD swizzle (round-8 win): contiguous logical-block runs per XCD.
// THIS ROUND: double-buffered at BK=32 with TOTAL LDS UNCHANGED (32 KB) —
// dbuf pipelining without the m132 occupancy trap (R9's 64 KB dbuf lost
// ~6 us to blocks/CU). GLD16 staging uses no data VGPRs (no spill risk);
// buffers statically named via compile-time byte offsets (rule #20).
// Per K-pair: vmcnt(4);bar;COMPUTE(buf0);bar;STAGE->buf0(k+64); then
// symmetric for buf1. 4 prefetch loads stay in flight across every
// barrier; vmcnt(0) only at the tail.
// BK=32 swizzle: physical chunk = quad ^ ((row>>1)&3) on BOTH the
// pre-swizzled global source and the ds_read -> banks = 16*(row&1) +
// 4*(quad^((row>>1)&3)) covers 16 banks x 2 parities = 2 lanes/bank (free).
template<int BF16OUT>
__global__ __launch_bounds__(256, 4) void gemm_bt(const unsigned short* __restrict__ A,
                                                  const unsigned short* __restrict__ Bt,
                                                  void* __restrict__ Cc,
                                                  int M, int N, int K){
    __shared__ __align__(16) unsigned short As[2][128*32];   // 16 KB
    __shared__ __align__(16) unsigned short Bs[2][128*32];   // 16 KB
    const int tid  = threadIdx.x;
    const int wid  = tid >> 6;
    const int lane = tid & 63;
    const int wm   = wid >> 1;
    const int wn   = wid & 1;
    const int l16  = lane & 15;
    const int quad = lane >> 4;

    int bm, bn;
    {
        int gx = gridDim.x;
        int p  = blockIdx.y * gx + blockIdx.x;       // physical linear id
        int nb = gx * gridDim.y;
        int l  = (p & 7) * (nb >> 3) + (p >> 3);     // XCD-chunked logical id
        bn = (l % gx) * 128;
        bm = (l / gx) * 128;
    }

    // staging addresses: thread stages chunks tid (rows 0-63) and tid+256
    // (rows 64-127) of each matrix; (row>>1)&3 invariant under row+64.
    const unsigned short* gaA; const unsigned short* gbB;
    char* laA; char* lbB;
    {
        int row = tid >> 2, slot = tid & 3;
        int cg  = slot ^ ((row >> 1) & 3);
        gaA = A  + (size_t)(bm+row)*K + cg*8;
        gbB = Bt + (size_t)(bn+row)*K + cg*8;
        laA = (char*)&As[0][0] + (size_t)tid*16;
        lbB = (char*)&Bs[0][0] + (size_t)tid*16;
    }
    const size_t gstep = (size_t)64 * K;   // +64 rows

    f32x4 acc[4][4] = {};

// stage one 128x32 slab pair into buffer at byte offset BOFF (0 or 8192)
#define STAGE32(KOFF, BOFF) do { \
    GLD16(gaA + (KOFF),         laA + (BOFF)); \
    GLD16(gaA + gstep + (KOFF), laA + (BOFF) + 4096); \
    GLD16(gbB + (KOFF),         lbB + (BOFF)); \
    GLD16(gbB + gstep + (KOFF), lbB + (BOFF) + 4096); \
} while(0)

// compute one BK=32 slab from statically-named buffers (16 MFMAs)
#define COMPUTE32(ASB, BSB) do { \
    const unsigned short* As_ = (ASB); \
    const unsigned short* Bs_ = (BSB); \
    bf16x8 af[4], bfr[4]; \
    _Pragma("unroll") \
    for (int i = 0; i < 4; ++i){ \
        int row = wm*64 + i*16 + l16; \
        int pc  = quad ^ ((row >> 1) & 3); \
        af[i] = *(const bf16x8*)(As_ + row*32 + pc*8); \
    } \
    _Pragma("unroll") \
    for (int j = 0; j < 4; ++j){ \
        int row = wn*64 + j*16 + l16; \
        int pc  = quad ^ ((row >> 1) & 3); \
        bfr[j] = *(const bf16x8*)(Bs_ + row*32 + pc*8); \
    } \
    _Pragma("unroll") \
    for (int i = 0; i < 4; ++i) \
        _Pragma("unroll") \
        for (int j = 0; j < 4; ++j) \
            acc[i][j] = __builtin_amdgcn_mfma_f32_16x16x32_bf16(af[i], bfr[j], acc[i][j], 0, 0, 0); \
} while(0)

    // prologue: fill both buffers (8 loads in flight)
    STAGE32(0, 0);
    STAGE32(32, 8192);

    for (int k0 = 0; k0 < K; k0 += 64){
        // ---- buf0: K-slab k0 ----
        asm volatile("s_waitcnt vmcnt(4)" ::: "memory");   // buf0's 4 retired
        __builtin_amdgcn_s_barrier();
        COMPUTE32(&As[0][0], &Bs[0][0]);
        __builtin_amdgcn_s_barrier();                      // buf0 reads done
        if (k0 + 64 < K) STAGE32(k0 + 64, 0);
        // ---- buf1: K-slab k0+32 ----
        if (k0 + 64 < K) asm volatile("s_waitcnt vmcnt(4)" ::: "memory");
        else             asm volatile("s_waitcnt vmcnt(0)" ::: "memory");
        __builtin_amdgcn_s_barrier();
        COMPUTE32(&As[1][0], &Bs[1][0]);
        __builtin_amdgcn_s_barrier();                      // buf1 reads done
        if (k0 + 96 < K) STAGE32(k0 + 96, 8192);
    }
#undef STAGE32
#undef COMPUTE32

    #pragma unroll
    for (int i = 0; i < 4; ++i){
        int row0 = wm*64 + i*16 + quad*4;
        #pragma unroll
        for (int j = 0; j < 4; ++j){
            int col = bn + wn*64 + j*16 + l16;
            #pragma unroll
            for (int r = 0; r < 4; ++r){
                if (BF16OUT)
                    ((unsigned short*)Cc)[(size_t)(bm + row0 + r)*N + col] = f2b(acc[i][j][r]);
                else
                    ((float*)Cc)[(size_t)(bm + row0 + r)*N + col] = acc[i][j][r];
            }
        }
    }
}

// ---------------- fused K norm+RoPE + V transpose ---------------------------
// (round-11 win) Grid (TT/64, HKV, BB), 256 threads.
__global__ __launch_bounds__(256) void prep_kv(const unsigned short* __restrict__ QKVb,
                                               const float* __restrict__ kw,
                                               unsigned short* __restrict__ ka,
                                               unsigned short* __restrict__ vat){
    __shared__ unsigned short tile[64][72];
    const int tid = threadIdx.x;
    const int tblk = blockIdx.x, n = blockIdx.y, b = blockIdx.z;

    // V tile -> LDS (issues before the K passes, consumed after)
    #pragma unroll
    for (int it = 0; it < 2; ++it){
        int i = it*256 + tid;           // 0..511 chunks of 8 bf16
        int r = i >> 3, c = i & 7;
        uint4 v = *(const uint4*)(QKVb + ((size_t)(b*TT + tblk*64 + r))*1536 + 1280 + n*64 + c*8);
        *(uint4*)(&tile[r][c*8]) = v;
    }

    // K norm + RoPE: wave w handles row p*4+w each pass
    {
        const int rr = tid >> 6, lane = tid & 63;
        const float kwl = kw[lane];
        const float invf = exp2f(-(float)(lane & 31) * (13.287712379549449f/32.0f));
        #pragma unroll 4
        for (int p = 0; p < 16; ++p){
            int t = tblk*64 + p*4 + rr;
            float val = b2f(QKVb[((size_t)(b*TT + t))*1536 + 1024 + n*64 + lane]);
            float ss = val*val;
            #pragma unroll
            for (int off = 32; off > 0; off >>= 1) ss += __shfl_xor(ss, off, 64);
            float normed = val * rsqrtf(ss*(1.0f/64.0f) + 1e-6f) * kwl;
            float s, c;
            sincosf((float)t * invf, &s, &c);
            float other = __shfl_xor(normed, 32, 64);
            float outv = (lane < 32) ? (normed*c + other*s) : (-other*s + normed*c);
            ka[(((size_t)(b*HKV + n))*TT + t)*HD + lane] = f2b(outv);
        }
    }

    __syncthreads();
    const int d = tid >> 2, tseg = tid & 3;
    unsigned short tmp[16];
    #pragma unroll
    for (int i = 0; i < 16; ++i) tmp[i] = tile[tseg*16 + i][d];
    size_t off = (((size_t)(b*HKV + n))*HD + d)*TT + tblk*64 + tseg*16;
    *(uint4*)(vat + off)     = *(const uint4*)tmp;
    *(uint4*)(vat + off + 8) = *(const uint4*)(tmp + 8);
}

// ---------------- Flash attention: XCD-clustered pair-blocks, fused Q-norm --
// EXACT round-2 kernel (best measured: 63 us fast machine / 79.5 slow —
// identical counters, machine variance). Rounds 3-5,7 proved any added live
// state crosses the 128-VGPR cap of __launch_bounds__(512,4) and spills.
// DO NOT add state here.
__global__ __launch_bounds__(512, 4) void attn_mfma(const unsigned short* __restrict__ QKVb,
                                                    const unsigned short* __restrict__ ka,
                                                    const unsigned short* __restrict__ vat,
                                                    const float* __restrict__ qw,
                                                    unsigned short* __restrict__ ya){
    __shared__ __align__(16) unsigned short Ks[64*64];    // [key][chunk^(key&7)]
    __shared__ __align__(16) unsigned short Vts[64*64];   // [d][chunk^(d&7)]
    __shared__ __align__(16) unsigned short Ps[8][32*72]; // per-wave [q32][key]

    const int tid = threadIdx.x;
    const int wave = tid >> 6, lane = tid & 63;
    const int l16 = lane & 15, quad = lane >> 4;
    const int n = blockIdx.x, b = blockIdx.y, iz = blockIdx.z;
    const int ib = (iz < 8) ? iz : 23 - iz;    // complementary pairing
    const int head = wave & 3, sub = wave >> 2;
    const int h = n*4 + head;
    const int R0[2] = { ib*32 + sub*16, (31-ib)*32 + sub*16 };

    // ---- fused Q RMSNorm + RoPE preamble ----
    bf16x8 qf[2][2];
    {
        float invf[8], rw0[8], rw1[8];
        #pragma unroll
        for (int j = 0; j < 8; ++j){
            int i = quad*8 + j;
            invf[j] = exp2f(-(float)i * (13.287712379549449f/32.0f));
            rw0[j] = qw[i]; rw1[j] = qw[i + 32];
        }
        #pragma unroll
        for (int h2 = 0; h2 < 2; ++h2){
            const int t = R0[h2] + l16;
            const unsigned short* qp = QKVb + ((size_t)(b*TT + t))*1536 + h*64 + quad*8;
            float x0[8], x1[8];
            {
                uint4 a = *(const uint4*)qp;
                uint4 c = *(const uint4*)(qp + 32);
                const unsigned short* pa = (const unsigned short*)&a;
                const unsigned short* pc = (const unsigned short*)&c;
                #pragma unroll
                for (int j = 0; j < 8; ++j){ x0[j] = b2f(pa[j]); x1[j] = b2f(pc[j]); }
            }
            float ss = 0.f;
            #pragma unroll
            for (int j = 0; j < 8; ++j) ss += x0[j]*x0[j] + x1[j]*x1[j];
            ss += __shfl_xor(ss, 16, 64);
            ss += __shfl_xor(ss, 32, 64);
            float rn = rsqrtf(ss*(1.0f/64.0f) + 1e-6f);
            unsigned short o0[8], o1[8];
            #pragma unroll
            for (int j = 0; j < 8; ++j){
                float s, c;
                sincosf((float)t * invf[j], &s, &c);
                float n0 = x0[j]*rn*rw0[j];
                float n1 = x1[j]*rn*rw1[j];
                o0[j] = f2b(n0*c + n1*s);
                o1[j] = f2b(n1*c - n0*s);
            }
            qf[h2][0] = *(const bf16x8*)o0;
            qf[h2][1] = *(const bf16x8*)o1;
        }
    }

    const unsigned short* kbase = ka  + ((size_t)(b*HKV + n))*TT*HD;
    const unsigned short* vbase = vat + ((size_t)(b*HKV + n))*HD*TT;

    // staging: each thread stages one 16B K chunk and one 16B V chunk
    const unsigned short* gk; const unsigned short* gv;
    char* lk; char* lv;
    {
        int row = tid >> 3, slot = tid & 7;
        int cg = slot ^ (row & 7);
        gk = kbase + (size_t)row*HD + cg*8;
        gv = vbase + (size_t)row*TT + cg*8;
        lk = (char*)Ks  + (size_t)tid*16;
        lv = (char*)Vts + (size_t)tid*16;
    }

    f32x4 o[2][4] = {};
    f32x4 lacc[2] = {};
    unsigned short* PsW = &Ps[wave][0];

    // ones B-operand fragment for the l MFMA (bf16 1.0 = 0x3f80)
    bf16x8 ones;
    #pragma unroll
    for (int j = 0; j < 8; ++j) ones[j] = (short)0x3f80;

    // cubic-tanh softcap constants
    const float A1 = 0.125f * LOG2E;                 // raw * A1 = s*log2e
    const float B3 = LOG2E / 3840000.0f;             // raw^3 coeff (s^3/7500)
    const int sw = l16 & 7;
    const int ktmax = (1023 - 32*ib) >> 6;

    for (int kt = 0; kt <= ktmax; ++kt){
        const int k0 = kt*64;
        __syncthreads();
        GLD16(gk + (size_t)k0*HD, lk);
        GLD16(gv + k0, lv);
        __syncthreads();

        const bool act0 = (k0 <= R0[0] + 15);
        // S^T = K Q^T : D[m=key][n=q]; key = j*16+quad*4+r, q = l16
        f32x4 sacc[2][4];
        __builtin_amdgcn_s_setprio(1);
        #pragma unroll
        for (int j = 0; j < 4; ++j){
            const unsigned short* kr = Ks + (j*16 + l16)*64;
            bf16x8 kf0 = *(const bf16x8*)(kr + (quad ^ sw)*8);
            bf16x8 kf1 = *(const bf16x8*)(kr + ((quad+4) ^ sw)*8);
            if (act0){
                f32x4 z = {};
                z = __builtin_amdgcn_mfma_f32_16x16x32_bf16(kf0, qf[0][0], z, 0,0,0);
                sacc[0][j] = __builtin_amdgcn_mfma_f32_16x16x32_bf16(kf1, qf[0][1], z, 0,0,0);
            }
            {
                f32x4 z = {};
                z = __builtin_amdgcn_mfma_f32_16x16x32_bf16(kf0, qf[1][0], z, 0,0,0);
                sacc[1][j] = __builtin_amdgcn_mfma_f32_16x16x32_bf16(kf1, qf[1][1], z, 0,0,0);
            }
        }
        __builtin_amdgcn_s_setprio(0);
        // softmax + P write per window
        #pragma unroll
        for (int h2 = 0; h2 < 2; ++h2){
            if (h2 == 0 && !act0) continue;
            const int Rb = R0[h2];
            const bool full = (k0 + 63 <= Rb);
            const int qrow = Rb + l16;
            #pragma unroll
            for (int j = 0; j < 4; ++j){
                float pv[4];
                #pragma unroll
                for (int r = 0; r < 4; ++r){
                    float sr = sacc[h2][j][r];
                    float u  = sr*sr;
                    float p  = exp2f(sr * fmaf(u, -B3, A1));
                    if (!full && (k0 + j*16 + quad*4 + r > qrow)) p = 0.f;
                    pv[r] = p;
                }
                unsigned int pk0, pk1;
                asm("v_cvt_pk_bf16_f32 %0, %1, %2" : "=v"(pk0) : "v"(pv[0]), "v"(pv[1]));
                asm("v_cvt_pk_bf16_f32 %0, %1, %2" : "=v"(pk1) : "v"(pv[2]), "v"(pv[3]));
                *(uint2*)(PsW + (h2*16 + l16)*72 + j*16 + quad*4) = make_uint2(pk0, pk1);
            }
        }
        // PV: A = P[q][key], B = Vt[d][key]; vf shared across both windows
        bf16x8 pf[2][2];
        if (act0){
            pf[0][0] = *(const bf16x8*)(PsW + l16*72 + quad*8);
            pf[0][1] = *(const bf16x8*)(PsW + l16*72 + quad*8 + 32);
        }
        pf[1][0] = *(const bf16x8*)(PsW + (16 + l16)*72 + quad*8);
        pf[1][1] = *(const bf16x8*)(PsW + (16 + l16)*72 + quad*8 + 32);
        __builtin_amdgcn_s_setprio(1);
        // l = P @ ones (consistent with bf16 P by construction)
        if (act0){
            lacc[0] = __builtin_amdgcn_mfma_f32_16x16x32_bf16(pf[0][0], ones, lacc[0], 0,0,0);
            lacc[0] = __builtin_amdgcn_mfma_f32_16x16x32_bf16(pf[0][1], ones, lacc[0], 0,0,0);
        }
        lacc[1] = __builtin_amdgcn_mfma_f32_16x16x32_bf16(pf[1][0], ones, lacc[1], 0,0,0);
        lacc[1] = __builtin_amdgcn_mfma_f32_16x16x32_bf16(pf[1][1], ones, lacc[1], 0,0,0);
        #pragma unroll
        for (int jd = 0; jd < 4; ++jd){
            const unsigned short* vr = Vts + (jd*16 + l16)*64;
            bf16x8 vf0 = *(const bf16x8*)(vr + (quad ^ sw)*8);
            bf16x8 vf1 = *(const bf16x8*)(vr + ((quad+4) ^ sw)*8);
            if (act0){
                o[0][jd] = __builtin_amdgcn_mfma_f32_16x16x32_bf16(pf[0][0], vf0, o[0][jd], 0,0,0);
                o[0][jd] = __builtin_amdgcn_mfma_f32_16x16x32_bf16(pf[0][1], vf1, o[0][jd], 0,0,0);
            }
            o[1][jd] = __builtin_amdgcn_mfma_f32_16x16x32_bf16(pf[1][0], vf0, o[1][jd], 0,0,0);
            o[1][jd] = __builtin_amdgcn_mfma_f32_16x16x32_bf16(pf[1][1], vf1, o[1][jd], 0,0,0);
        }
        __builtin_amdgcn_s_setprio(0);
    }

    // epilogue: lacc[h2][r] is l for q-row (quad*4+r) -- no shuffles needed
    #pragma unroll
    for (int h2 = 0; h2 < 2; ++h2){
        const int Rb = R0[h2];
        #pragma unroll
        for (int r = 0; r < 4; ++r){
            float linv = __builtin_amdgcn_rcpf(lacc[h2][r]);
            int t = Rb + quad*4 + r;
            #pragma unroll
            for (int jd = 0; jd < 4; ++jd)
                ya[(((size_t)(b*TT + t))*HH + h)*HD + jd*16 + l16] = f2b(o[h2][jd][r]*linv);
        }
    }
}

// ---------------- launch ----------------------------------------------------
extern "C" void kernel_launch(void* const* d_in, const int* in_sizes, int n_in,
                              void* d_out, int out_size, void* d_ws, size_t ws_size,
                              hipStream_t stream) {
    const float* x    = (const float*)d_in[0];
    const float* w_q  = (const float*)d_in[1];
    const float* w_kv = (const float*)d_in[2];
    const float* w_c  = (const float*)d_in[3];
    const float* qw   = (const float*)d_in[4];
    const float* kw   = (const float*)d_in[5];
    float* out = (float*)d_out;

    char* ws = (char*)d_ws;
    unsigned short* xb    = (unsigned short*)(ws);                    // 16 MB
    unsigned short* wqkvb = (unsigned short*)(ws + ((size_t)16<<20)); // 3 MB
    unsigned short* wcb   = (unsigned short*)(ws + ((size_t)19<<20)); // 2 MB
    unsigned short* QKVb  = (unsigned short*)(ws + ((size_t)21<<20)); // 24 MB
    unsigned short* ka    = (unsigned short*)(ws + ((size_t)45<<20)); // 4 MB
    unsigned short* vat   = (unsigned short*)(ws + ((size_t)49<<20)); // 4 MB
    unsigned short* ya    = (unsigned short*)(ws + ((size_t)53<<20)); // 16 MB

    // 1) convert all inputs to bf16 (one kernel)
    cvt_all<<<dim3(2752512/256), 256, 0, stream>>>(x, w_q, w_kv, w_c, xb, wqkvb, wcb);

    // 2) fused QKV = x @ [w_q; w_kv]^T  (8192 x 1536 x 1024), bf16 out
    gemm_bt<1><<<dim3(1536/128, MM/128), 256, 0, stream>>>(xb, wqkvb, (void*)QKVb, MM, 1536, CC);

    // 3) fused K norm+RoPE + V transpose
    prep_kv<<<dim3(TT/64, HKV, BB), 256, 0, stream>>>(QKVb, kw, ka, vat);

    // 4) flash attention (exact round-2 kernel)
    attn_mfma<<<dim3(HKV, BB, 16), 512, 0, stream>>>(QKVb, ka, vat, qw, ya);

    // 5) out = y @ w_c^T (fp32 out)
    gemm_bt<0><<<dim3(CC/128, MM/128), 256, 0, stream>>>(ya, wcb, (void*)out, MM, CC, CC);
}

// Round 13
// 204.161 us; speedup vs baseline: 1.0375x; 1.0375x over previous
//
#include <hip/hip_runtime.h>
#include <math.h>

// Problem constants
#define BB 8
#define TT 1024
#define CC 1024
#define HH 16
#define HKV 4
#define HD 64
#define MM (BB*TT)   // 8192
#define LOG2E 1.4426950408889634f

typedef __attribute__((ext_vector_type(8))) short bf16x8;
typedef __attribute__((ext_vector_type(4))) float f32x4;

__device__ __forceinline__ float b2f(unsigned short x){
    union{unsigned int i; float f;} u; u.i = ((unsigned int)x)<<16; return u.f;
}
__device__ __forceinline__ unsigned short f2b(float f){
    union{float f; unsigned int i;} u; u.f = f;
    unsigned int r = u.i + 0x7fffu + ((u.i>>16)&1u);
    return (unsigned short)(r>>16);
}

// async 16B global -> LDS (gfx950 global_load_lds_dwordx4)
#define GLD16(gp, lp) __builtin_amdgcn_global_load_lds( \
    (__attribute__((address_space(1))) void*)(gp), \
    (__attribute__((address_space(3))) void*)(lp), 16, 0, 0)

// ---------------- fp32 -> bf16 conversion (all inputs, one kernel) ----------
__global__ __launch_bounds__(256) void cvt_all(const float* __restrict__ x,
                                               const float* __restrict__ w_q,
                                               const float* __restrict__ w_kv,
                                               const float* __restrict__ w_c,
                                               unsigned short* __restrict__ xb,
                                               unsigned short* __restrict__ wqkvb,
                                               unsigned short* __restrict__ wcb){
    int i = blockIdx.x*256 + threadIdx.x;
    const float* src; unsigned short* dst; int off;
    if (i < 2097152)      { src = x;    dst = xb;              off = i; }
    else if (i < 2359296) { src = w_q;  dst = wqkvb;           off = i - 2097152; }
    else if (i < 2490368) { src = w_kv; dst = wqkvb + 1048576; off = i - 2359296; }
    else                  { src = w_c;  dst = wcb;             off = i - 2490368; }
    float4 f = ((const float4*)src)[off];
    ushort4 o;
    o.x = f2b(f.x); o.y = f2b(f.y); o.z = f2b(f.z); o.w = f2b(f.w);
    ((ushort4*)dst)[off] = o;
}

// ---------------- bf16 MFMA GEMM: C = A(MxK) * Bt(NxK)^T, BK=64 -------------
// XOR-swizzled LDS (source-side permutation, GLD16 dst stays contiguous).
// T1 XCD swizzle (round-8 win): remap physical block id so each XCD gets a
// contiguous run of logical blocks (8 bm panels x all bn) -> L2-resident
// working set. Requires total blocks % 8 == 0 (768, 512 qualify).
// SINGLE-buffered BK=64 staging (32 KB LDS). PROVEN OPTIMAL for this
// structure: R9 dbuf@64KB lost ~6 us (m132 occupancy trap), R12 dbuf@32KB/
// BK=32 lost ~6 us (doubled barrier count). Do not pipeline this loop.
// __launch_bounds__(256,4) caps VGPR at 128 -> 4 blocks/CU (R11 win).
template<int BF16OUT>
__global__ __launch_bounds__(256, 4) void gemm_bt(const unsigned short* __restrict__ A,
                                                  const unsigned short* __restrict__ Bt,
                                                  void* __restrict__ Cc,
                                                  int M, int N, int K){
    __shared__ __align__(16) unsigned short As[128*64];
    __shared__ __align__(16) unsigned short Bs[128*64];
    const int tid  = threadIdx.x;
    const int wid  = tid >> 6;
    const int lane = tid & 63;
    const int wm   = wid >> 1;
    const int wn   = wid & 1;
    const int l16  = lane & 15;
    const int quad = lane >> 4;

    int bm, bn;
    {
        int gx = gridDim.x;
        int p  = blockIdx.y * gx + blockIdx.x;       // physical linear id
        int nb = gx * gridDim.y;
        int l  = (p & 7) * (nb >> 3) + (p >> 3);     // XCD-chunked logical id
        bn = (l % gx) * 128;
        bm = (l / gx) * 128;
    }

    const unsigned short* ga[4]; const unsigned short* gb[4];
    char* la[4]; char* lb[4];
    {
        int rbase = tid >> 3, c_lds = tid & 7;
        #pragma unroll
        for (int it = 0; it < 4; ++it){
            int row = it*32 + rbase;
            int cg  = c_lds ^ (row & 7);
            ga[it] = A  + (size_t)(bm+row)*K + cg*8;
            gb[it] = Bt + (size_t)(bn+row)*K + cg*8;
            la[it] = (char*)As + (size_t)(it*256 + tid)*16;
            lb[it] = (char*)Bs + (size_t)(it*256 + tid)*16;
        }
    }

    f32x4 acc[4][4] = {};

    for (int k0 = 0; k0 < K; k0 += 64){
        __syncthreads();
        #pragma unroll
        for (int it = 0; it < 4; ++it){
            GLD16(ga[it] + k0, la[it]);
            GLD16(gb[it] + k0, lb[it]);
        }
        __syncthreads();

        #pragma unroll
        for (int kh = 0; kh < 2; ++kh){
            bf16x8 af[4], bfr[4];
            #pragma unroll
            for (int i = 0; i < 4; ++i){
                int row = wm*64 + i*16 + l16;
                int ch  = (kh*4 + quad) ^ (row & 7);
                af[i] = *(const bf16x8*)(As + row*64 + ch*8);
            }
            #pragma unroll
            for (int j = 0; j < 4; ++j){
                int row = wn*64 + j*16 + l16;
                int ch  = (kh*4 + quad) ^ (row & 7);
                bfr[j] = *(const bf16x8*)(Bs + row*64 + ch*8);
            }
            #pragma unroll
            for (int i = 0; i < 4; ++i)
                #pragma unroll
                for (int j = 0; j < 4; ++j)
                    acc[i][j] = __builtin_amdgcn_mfma_f32_16x16x32_bf16(af[i], bfr[j], acc[i][j], 0, 0, 0);
        }
    }

    #pragma unroll
    for (int i = 0; i < 4; ++i){
        int row0 = wm*64 + i*16 + quad*4;
        #pragma unroll
        for (int j = 0; j < 4; ++j){
            int col = bn + wn*64 + j*16 + l16;
            #pragma unroll
            for (int r = 0; r < 4; ++r){
                if (BF16OUT)
                    ((unsigned short*)Cc)[(size_t)(bm + row0 + r)*N + col] = f2b(acc[i][j][r]);
                else
                    ((float*)Cc)[(size_t)(bm + row0 + r)*N + col] = acc[i][j][r];
            }
        }
    }
}

// ---------------- fused K norm+RoPE + V transpose ---------------------------
// (round-11 win) Grid (TT/64, HKV, BB), 256 threads.
__global__ __launch_bounds__(256) void prep_kv(const unsigned short* __restrict__ QKVb,
                                               const float* __restrict__ kw,
                                               unsigned short* __restrict__ ka,
                                               unsigned short* __restrict__ vat){
    __shared__ unsigned short tile[64][72];
    const int tid = threadIdx.x;
    const int tblk = blockIdx.x, n = blockIdx.y, b = blockIdx.z;

    // V tile -> LDS (issues before the K passes, consumed after)
    #pragma unroll
    for (int it = 0; it < 2; ++it){
        int i = it*256 + tid;           // 0..511 chunks of 8 bf16
        int r = i >> 3, c = i & 7;
        uint4 v = *(const uint4*)(QKVb + ((size_t)(b*TT + tblk*64 + r))*1536 + 1280 + n*64 + c*8);
        *(uint4*)(&tile[r][c*8]) = v;
    }

    // K norm + RoPE: wave w handles row p*4+w each pass
    {
        const int rr = tid >> 6, lane = tid & 63;
        const float kwl = kw[lane];
        const float invf = exp2f(-(float)(lane & 31) * (13.287712379549449f/32.0f));
        #pragma unroll 4
        for (int p = 0; p < 16; ++p){
            int t = tblk*64 + p*4 + rr;
            float val = b2f(QKVb[((size_t)(b*TT + t))*1536 + 1024 + n*64 + lane]);
            float ss = val*val;
            #pragma unroll
            for (int off = 32; off > 0; off >>= 1) ss += __shfl_xor(ss, off, 64);
            float normed = val * rsqrtf(ss*(1.0f/64.0f) + 1e-6f) * kwl;
            float s, c;
            sincosf((float)t * invf, &s, &c);
            float other = __shfl_xor(normed, 32, 64);
            float outv = (lane < 32) ? (normed*c + other*s) : (-other*s + normed*c);
            ka[(((size_t)(b*HKV + n))*TT + t)*HD + lane] = f2b(outv);
        }
    }

    __syncthreads();
    const int d = tid >> 2, tseg = tid & 3;
    unsigned short tmp[16];
    #pragma unroll
    for (int i = 0; i < 16; ++i) tmp[i] = tile[tseg*16 + i][d];
    size_t off = (((size_t)(b*HKV + n))*HD + d)*TT + tblk*64 + tseg*16;
    *(uint4*)(vat + off)     = *(const uint4*)tmp;
    *(uint4*)(vat + off + 8) = *(const uint4*)(tmp + 8);
}

// ---------------- Flash attention: XCD-clustered pair-blocks, fused Q-norm --
// EXACT round-2 kernel (best measured: 63 us fast machine / 79.5 slow —
// identical counters, machine variance). Rounds 3-5,7 proved any added live
// state crosses the 128-VGPR cap of __launch_bounds__(512,4) and spills.
// DO NOT add state here.
__global__ __launch_bounds__(512, 4) void attn_mfma(const unsigned short* __restrict__ QKVb,
                                                    const unsigned short* __restrict__ ka,
                                                    const unsigned short* __restrict__ vat,
                                                    const float* __restrict__ qw,
                                                    unsigned short* __restrict__ ya){
    __shared__ __align__(16) unsigned short Ks[64*64];    // [key][chunk^(key&7)]
    __shared__ __align__(16) unsigned short Vts[64*64];   // [d][chunk^(d&7)]
    __shared__ __align__(16) unsigned short Ps[8][32*72]; // per-wave [q32][key]

    const int tid = threadIdx.x;
    const int wave = tid >> 6, lane = tid & 63;
    const int l16 = lane & 15, quad = lane >> 4;
    const int n = blockIdx.x, b = blockIdx.y, iz = blockIdx.z;
    const int ib = (iz < 8) ? iz : 23 - iz;    // complementary pairing
    const int head = wave & 3, sub = wave >> 2;
    const int h = n*4 + head;
    const int R0[2] = { ib*32 + sub*16, (31-ib)*32 + sub*16 };

    // ---- fused Q RMSNorm + RoPE preamble ----
    bf16x8 qf[2][2];
    {
        float invf[8], rw0[8], rw1[8];
        #pragma unroll
        for (int j = 0; j < 8; ++j){
            int i = quad*8 + j;
            invf[j] = exp2f(-(float)i * (13.287712379549449f/32.0f));
            rw0[j] = qw[i]; rw1[j] = qw[i + 32];
        }
        #pragma unroll
        for (int h2 = 0; h2 < 2; ++h2){
            const int t = R0[h2] + l16;
            const unsigned short* qp = QKVb + ((size_t)(b*TT + t))*1536 + h*64 + quad*8;
            float x0[8], x1[8];
            {
                uint4 a = *(const uint4*)qp;
                uint4 c = *(const uint4*)(qp + 32);
                const unsigned short* pa = (const unsigned short*)&a;
                const unsigned short* pc = (const unsigned short*)&c;
                #pragma unroll
                for (int j = 0; j < 8; ++j){ x0[j] = b2f(pa[j]); x1[j] = b2f(pc[j]); }
            }
            float ss = 0.f;
            #pragma unroll
            for (int j = 0; j < 8; ++j) ss += x0[j]*x0[j] + x1[j]*x1[j];
            ss += __shfl_xor(ss, 16, 64);
            ss += __shfl_xor(ss, 32, 64);
            float rn = rsqrtf(ss*(1.0f/64.0f) + 1e-6f);
            unsigned short o0[8], o1[8];
            #pragma unroll
            for (int j = 0; j < 8; ++j){
                float s, c;
                sincosf((float)t * invf[j], &s, &c);
                float n0 = x0[j]*rn*rw0[j];
                float n1 = x1[j]*rn*rw1[j];
                o0[j] = f2b(n0*c + n1*s);
                o1[j] = f2b(n1*c - n0*s);
            }
            qf[h2][0] = *(const bf16x8*)o0;
            qf[h2][1] = *(const bf16x8*)o1;
        }
    }

    const unsigned short* kbase = ka  + ((size_t)(b*HKV + n))*TT*HD;
    const unsigned short* vbase = vat + ((size_t)(b*HKV + n))*HD*TT;

    // staging: each thread stages one 16B K chunk and one 16B V chunk
    const unsigned short* gk; const unsigned short* gv;
    char* lk; char* lv;
    {
        int row = tid >> 3, slot = tid & 7;
        int cg = slot ^ (row & 7);
        gk = kbase + (size_t)row*HD + cg*8;
        gv = vbase + (size_t)row*TT + cg*8;
        lk = (char*)Ks  + (size_t)tid*16;
        lv = (char*)Vts + (size_t)tid*16;
    }

    f32x4 o[2][4] = {};
    f32x4 lacc[2] = {};
    unsigned short* PsW = &Ps[wave][0];

    // ones B-operand fragment for the l MFMA (bf16 1.0 = 0x3f80)
    bf16x8 ones;
    #pragma unroll
    for (int j = 0; j < 8; ++j) ones[j] = (short)0x3f80;

    // cubic-tanh softcap constants
    const float A1 = 0.125f * LOG2E;                 // raw * A1 = s*log2e
    const float B3 = LOG2E / 3840000.0f;             // raw^3 coeff (s^3/7500)
    const int sw = l16 & 7;
    const int ktmax = (1023 - 32*ib) >> 6;

    for (int kt = 0; kt <= ktmax; ++kt){
        const int k0 = kt*64;
        __syncthreads();
        GLD16(gk + (size_t)k0*HD, lk);
        GLD16(gv + k0, lv);
        __syncthreads();

        const bool act0 = (k0 <= R0[0] + 15);
        // S^T = K Q^T : D[m=key][n=q]; key = j*16+quad*4+r, q = l16
        f32x4 sacc[2][4];
        __builtin_amdgcn_s_setprio(1);
        #pragma unroll
        for (int j = 0; j < 4; ++j){
            const unsigned short* kr = Ks + (j*16 + l16)*64;
            bf16x8 kf0 = *(const bf16x8*)(kr + (quad ^ sw)*8);
            bf16x8 kf1 = *(const bf16x8*)(kr + ((quad+4) ^ sw)*8);
            if (act0){
                f32x4 z = {};
                z = __builtin_amdgcn_mfma_f32_16x16x32_bf16(kf0, qf[0][0], z, 0,0,0);
                sacc[0][j] = __builtin_amdgcn_mfma_f32_16x16x32_bf16(kf1, qf[0][1], z, 0,0,0);
            }
            {
                f32x4 z = {};
                z = __builtin_amdgcn_mfma_f32_16x16x32_bf16(kf0, qf[1][0], z, 0,0,0);
                sacc[1][j] = __builtin_amdgcn_mfma_f32_16x16x32_bf16(kf1, qf[1][1], z, 0,0,0);
            }
        }
        __builtin_amdgcn_s_setprio(0);
        // softmax + P write per window
        #pragma unroll
        for (int h2 = 0; h2 < 2; ++h2){
            if (h2 == 0 && !act0) continue;
            const int Rb = R0[h2];
            const bool full = (k0 + 63 <= Rb);
            const int qrow = Rb + l16;
            #pragma unroll
            for (int j = 0; j < 4; ++j){
                float pv[4];
                #pragma unroll
                for (int r = 0; r < 4; ++r){
                    float sr = sacc[h2][j][r];
                    float u  = sr*sr;
                    float p  = exp2f(sr * fmaf(u, -B3, A1));
                    if (!full && (k0 + j*16 + quad*4 + r > qrow)) p = 0.f;
                    pv[r] = p;
                }
                unsigned int pk0, pk1;
                asm("v_cvt_pk_bf16_f32 %0, %1, %2" : "=v"(pk0) : "v"(pv[0]), "v"(pv[1]));
                asm("v_cvt_pk_bf16_f32 %0, %1, %2" : "=v"(pk1) : "v"(pv[2]), "v"(pv[3]));
                *(uint2*)(PsW + (h2*16 + l16)*72 + j*16 + quad*4) = make_uint2(pk0, pk1);
            }
        }
        // PV: A = P[q][key], B = Vt[d][key]; vf shared across both windows
        bf16x8 pf[2][2];
        if (act0){
            pf[0][0] = *(const bf16x8*)(PsW + l16*72 + quad*8);
            pf[0][1] = *(const bf16x8*)(PsW + l16*72 + quad*8 + 32);
        }
        pf[1][0] = *(const bf16x8*)(PsW + (16 + l16)*72 + quad*8);
        pf[1][1] = *(const bf16x8*)(PsW + (16 + l16)*72 + quad*8 + 32);
        __builtin_amdgcn_s_setprio(1);
        // l = P @ ones (consistent with bf16 P by construction)
        if (act0){
            lacc[0] = __builtin_amdgcn_mfma_f32_16x16x32_bf16(pf[0][0], ones, lacc[0], 0,0,0);
            lacc[0] = __builtin_amdgcn_mfma_f32_16x16x32_bf16(pf[0][1], ones, lacc[0], 0,0,0);
        }
        lacc[1] = __builtin_amdgcn_mfma_f32_16x16x32_bf16(pf[1][0], ones, lacc[1], 0,0,0);
        lacc[1] = __builtin_amdgcn_mfma_f32_16x16x32_bf16(pf[1][1], ones, lacc[1], 0,0,0);
        #pragma unroll
        for (int jd = 0; jd < 4; ++jd){
            const unsigned short* vr = Vts + (jd*16 + l16)*64;
            bf16x8 vf0 = *(const bf16x8*)(vr + (quad ^ sw)*8);
            bf16x8 vf1 = *(const bf16x8*)(vr + ((quad+4) ^ sw)*8);
            if (act0){
                o[0][jd] = __builtin_amdgcn_mfma_f32_16x16x32_bf16(pf[0][0], vf0, o[0][jd], 0,0,0);
                o[0][jd] = __builtin_amdgcn_mfma_f32_16x16x32_bf16(pf[0][1], vf1, o[0][jd], 0,0,0);
            }
            o[1][jd] = __builtin_amdgcn_mfma_f32_16x16x32_bf16(pf[1][0], vf0, o[1][jd], 0,0,0);
            o[1][jd] = __builtin_amdgcn_mfma_f32_16x16x32_bf16(pf[1][1], vf1, o[1][jd], 0,0,0);
        }
        __builtin_amdgcn_s_setprio(0);
    }

    // epilogue: lacc[h2][r] is l for q-row (quad*4+r) -- no shuffles needed
    #pragma unroll
    for (int h2 = 0; h2 < 2; ++h2){
        const int Rb = R0[h2];
        #pragma unroll
        for (int r = 0; r < 4; ++r){
            float linv = __builtin_amdgcn_rcpf(lacc[h2][r]);
            int t = Rb + quad*4 + r;
            #pragma unroll
            for (int jd = 0; jd < 4; ++jd)
                ya[(((size_t)(b*TT + t))*HH + h)*HD + jd*16 + l16] = f2b(o[h2][jd][r]*linv);
        }
    }
}

// ---------------- launch ----------------------------------------------------
extern "C" void kernel_launch(void* const* d_in, const int* in_sizes, int n_in,
                              void* d_out, int out_size, void* d_ws, size_t ws_size,
                              hipStream_t stream) {
    const float* x    = (const float*)d_in[0];
    const float* w_q  = (const float*)d_in[1];
    const float* w_kv = (const float*)d_in[2];
    const float* w_c  = (const float*)d_in[3];
    const float* qw   = (const float*)d_in[4];
    const float* kw   = (const float*)d_in[5];
    float* out = (float*)d_out;

    char* ws = (char*)d_ws;
    unsigned short* xb    = (unsigned short*)(ws);                    // 16 MB
    unsigned short* wqkvb = (unsigned short*)(ws + ((size_t)16<<20)); // 3 MB
    unsigned short* wcb   = (unsigned short*)(ws + ((size_t)19<<20)); // 2 MB
    unsigned short* QKVb  = (unsigned short*)(ws + ((size_t)21<<20)); // 24 MB
    unsigned short* ka    = (unsigned short*)(ws + ((size_t)45<<20)); // 4 MB
    unsigned short* vat   = (unsigned short*)(ws + ((size_t)49<<20)); // 4 MB
    unsigned short* ya    = (unsigned short*)(ws + ((size_t)53<<20)); // 16 MB

    // 1) convert all inputs to bf16 (one kernel)
    cvt_all<<<dim3(2752512/256), 256, 0, stream>>>(x, w_q, w_kv, w_c, xb, wqkvb, wcb);

    // 2) fused QKV = x @ [w_q; w_kv]^T  (8192 x 1536 x 1024), bf16 out
    gemm_bt<1><<<dim3(1536/128, MM/128), 256, 0, stream>>>(xb, wqkvb, (void*)QKVb, MM, 1536, CC);

    // 3) fused K norm+RoPE + V transpose
    prep_kv<<<dim3(TT/64, HKV, BB), 256, 0, stream>>>(QKVb, kw, ka, vat);

    // 4) flash attention (exact round-2 kernel)
    attn_mfma<<<dim3(HKV, BB, 16), 512, 0, stream>>>(QKVb, ka, vat, qw, ya);

    // 5) out = y @ w_c^T (fp32 out)
    gemm_bt<0><<<dim3(CC/128, MM/128), 256, 0, stream>>>(ya, wcb, (void*)out, MM, CC, CC);
}